// Round 15
// baseline (557.953 us; speedup 1.0000x reference)
//
#include <hip/hip_runtime.h>
#include <hip/hip_bf16.h>

typedef __hip_bfloat16 bf16;
typedef short s16x8 __attribute__((ext_vector_type(8)));
typedef float f32x4 __attribute__((ext_vector_type(4)));

#define T_  32
#define N_  1024
#define H_  256
#define E_  512
#define SD_ 16

static const long MBYTE = 1024L * 1024L;

__device__ __forceinline__ float b2f(bf16 v){ return __bfloat162float(v); }
__device__ __forceinline__ bf16  f2b(float v){ return __float2bfloat16(v); }

// direct global->LDS 16B async copy (dest = wave-uniform base + lane*16)
#define G2L16(gp, lp) __builtin_amdgcn_global_load_lds( \
    (const __attribute__((address_space(1))) void*)(const void*)(gp), \
    (__attribute__((address_space(3))) void*)(void*)(lp), 16, 0, 0)

// ---------------- fused prep: 13 transposes + pe + pack48 + idx_build ---------
struct TDesc { const float* src; int K; int N; bf16* dst; int ldT; float scale; };
struct PrepArgs {
    TDesc t[13];
    bf16* pe;
    const float* pa; const float* pb; const float* pc; float* po;
    const float* adj; unsigned short* IDX; int* CNT;
};

__global__ __launch_bounds__(256) void prep_kernel(PrepArgs P){
    int z = blockIdx.z;
    int tid = threadIdx.x;
    if (z < 13) {
        const TDesc d = P.t[z];
        int k0 = blockIdx.x * 32, n0 = blockIdx.y * 32;
        if (k0 >= d.K || n0 >= d.N) return;
        __shared__ float S[32][33];
        int r = tid >> 3, c4 = (tid & 7) * 4;
        #pragma unroll
        for (int u = 0; u < 4; ++u) {
            int k = k0 + r, n = n0 + c4 + u;
            S[r][c4 + u] = (k < d.K && n < d.N) ? d.src[(long)k * d.N + n] : 0.0f;
        }
        __syncthreads();
        int n = n0 + (tid >> 3);
        #pragma unroll
        for (int u = 0; u < 4; ++u) {
            int k = k0 + (tid & 7) * 4 + u;
            if (n < d.N && k < d.K)
                d.dst[(long)n * d.ldT + k] = f2b(S[(tid & 7) * 4 + u][tid >> 3] * d.scale);
        }
    } else if (z == 13) {
        int n = blockIdx.y * 32 + blockIdx.x;   // 0..1023
        int dd = tid;
        int i2 = (dd >> 1) * 2;
        float div = __expf((float)i2 * (-9.210340371976184f / 256.0f));
        float ang = (float)n * div;
        P.pe[n * 256 + dd] = f2b((dd & 1) ? __cosf(ang) : __sinf(ang));
    } else if (z == 14) {
        if (blockIdx.x || blockIdx.y) return;
        if (tid < 16) P.po[tid] = P.pa[tid];
        else if (tid < 32) P.po[tid] = P.pb[tid - 16];
        else if (tid < 48) P.po[tid] = P.pc[tid - 32];
    } else {
        int r = (z - 15) * 1024 + blockIdx.y * 32 + blockIdx.x;
        const float* arow = P.adj + ((long)r << 10);
        __shared__ int wcnt[4];
        int wv = tid >> 6, lane = tid & 63;
        int total = 0;
        unsigned short* out = P.IDX + (long)r * 128;
        #pragma unroll
        for (int u = 0; u < 4; ++u) {
            float av = arow[u * 256 + tid];
            unsigned long long mask = __ballot(av != 0.0f);
            if (lane == 0) wcnt[wv] = __popcll(mask);
            __syncthreads();
            int base = total;
            for (int w2 = 0; w2 < wv; ++w2) base += wcnt[w2];
            if (av != 0.0f) {
                int pos = base + __popcll(mask & ((1ull << lane) - 1ull));
                if (pos < 128) out[pos] = (unsigned short)(u * 256 + tid);
            }
            total += wcnt[0] + wcnt[1] + wcnt[2] + wcnt[3];
            __syncthreads();
        }
        if (tid == 0) P.CNT[r] = total < 128 ? total : 128;
    }
}

// ---------------- 128x128 MFMA GEMM, BK=64, swizzled LDS, z-dual -------------
template<int OP, bool NTF>
__global__ __launch_bounds__(256) void mfma_gemm128(
    const bf16* __restrict__ A, int lda,
    const bf16* BT0, const bf16* BT1, int ldbt0, int ldbt1,
    float* Cf0, float* Cf1, bf16* Cb0, bf16* Cb1, int ldc,
    int K, const float* bias0, const float* bias1, const bf16* resb)
{
    int z = blockIdx.z;
    const bf16* BT = z ? BT1 : BT0;
    int ldbt = z ? ldbt1 : ldbt0;
    float* Cf = z ? Cf1 : Cf0;
    bf16*  Cb = z ? Cb1 : Cb0;
    const float* bias = z ? bias1 : bias0;

    __shared__ short As[8192];
    __shared__ short Bs[8192];
    int tid = threadIdx.x;
    int w = tid >> 6, l = tid & 63;
    int wr = w >> 1, wc = w & 1;
    long row0 = (long)blockIdx.y * 128, col0 = (long)blockIdx.x * 128;
    const short* Ag = (const short*)A + row0 * lda;
    const short* Bg = (const short*)BT + col0 * ldbt;
    int strow = w * 8 + (l >> 3);
    int stcol = ((l & 7) ^ (l >> 3)) * 8;
    short* lA = As + w * 512 + l * 8;
    short* lB = Bs + w * 512 + l * 8;
    f32x4 acc[4][4] = {};
    for (int k0 = 0; k0 < K; k0 += 64) {
        #pragma unroll
        for (int i = 0; i < 4; ++i) {
            G2L16(Ag + (long)(strow + i * 32) * lda + k0 + stcol, lA + i * 2048);
            G2L16(Bg + (long)(strow + i * 32) * ldbt + k0 + stcol, lB + i * 2048);
        }
        __syncthreads();
        #pragma unroll
        for (int kk = 0; kk < 2; ++kk) {
            s16x8 af[4], bf[4];
            #pragma unroll
            for (int f = 0; f < 4; ++f) {
                int Ra = wr * 64 + f * 16 + (l & 15);
                af[f] = *(const s16x8*)&As[Ra * 64 + (((kk * 4 + (l >> 4)) ^ (Ra & 7)) * 8)];
                int Rb = wc * 64 + f * 16 + (l & 15);
                bf[f] = *(const s16x8*)&Bs[Rb * 64 + (((kk * 4 + (l >> 4)) ^ (Rb & 7)) * 8)];
            }
            #pragma unroll
            for (int fm = 0; fm < 4; ++fm)
                #pragma unroll
                for (int fn = 0; fn < 4; ++fn)
                    acc[fm][fn] = __builtin_amdgcn_mfma_f32_16x16x32_bf16(af[fm], bf[fn], acc[fm][fn], 0, 0, 0);
        }
        __syncthreads();
    }
    #pragma unroll
    for (int fm = 0; fm < 4; ++fm) {
        int er = (int)row0 + wr * 64 + fm * 16 + (l >> 4) * 4;
        #pragma unroll
        for (int fn = 0; fn < 4; ++fn) {
            int ec = (int)col0 + wc * 64 + fn * 16 + (l & 15);
            float bb = bias ? bias[ec] : 0.0f;
            #pragma unroll
            for (int rg = 0; rg < 4; ++rg) {
                long idx = (long)(er + rg) * ldc + ec;
                float v = acc[fm][fn][rg] + bb;
                if (resb) v += b2f(resb[idx]);
                if (OP == 1) v = v / (1.0f + __expf(-v));
                if (Cf) { if (NTF) __builtin_nontemporal_store(v, &Cf[idx]); else Cf[idx] = v; }
                if (Cb) Cb[idx] = f2b(v);
            }
        }
    }
}

// ---------------- 128x128 MFMA score, BK=64 swizzled (q pre-scaled 1/16) -----
__global__ __launch_bounds__(256) void score_mfma128(
    const bf16* __restrict__ Q, const bf16* __restrict__ Km,
    float* __restrict__ probs, float* __restrict__ logits,
    const float* __restrict__ gbp)
{
    int t = blockIdx.z;
    const short* Ag = (const short*)(Q  + (long)t * N_ * 256) + (long)blockIdx.y * 128 * 256;
    const short* Bg = (const short*)(Km + (long)t * N_ * 256) + (long)blockIdx.x * 128 * 256;
    __shared__ short As[8192];
    __shared__ short Bs[8192];
    int tid = threadIdx.x;
    int w = tid >> 6, l = tid & 63;
    int wr = w >> 1, wc = w & 1;
    int strow = w * 8 + (l >> 3);
    int stcol = ((l & 7) ^ (l >> 3)) * 8;
    short* lA = As + w * 512 + l * 8;
    short* lB = Bs + w * 512 + l * 8;
    f32x4 acc[4][4] = {};
    for (int k0 = 0; k0 < 256; k0 += 64) {
        #pragma unroll
        for (int i = 0; i < 4; ++i) {
            G2L16(Ag + (long)(strow + i * 32) * 256 + k0 + stcol, lA + i * 2048);
            G2L16(Bg + (long)(strow + i * 32) * 256 + k0 + stcol, lB + i * 2048);
        }
        __syncthreads();
        #pragma unroll
        for (int kk = 0; kk < 2; ++kk) {
            s16x8 af[4], bf[4];
            #pragma unroll
            for (int f = 0; f < 4; ++f) {
                int Ra = wr * 64 + f * 16 + (l & 15);
                af[f] = *(const s16x8*)&As[Ra * 64 + (((kk * 4 + (l >> 4)) ^ (Ra & 7)) * 8)];
                int Rb = wc * 64 + f * 16 + (l & 15);
                bf[f] = *(const s16x8*)&Bs[Rb * 64 + (((kk * 4 + (l >> 4)) ^ (Rb & 7)) * 8)];
            }
            #pragma unroll
            for (int fm = 0; fm < 4; ++fm)
                #pragma unroll
                for (int fn = 0; fn < 4; ++fn)
                    acc[fm][fn] = __builtin_amdgcn_mfma_f32_16x16x32_bf16(af[fm], bf[fn], acc[fm][fn], 0, 0, 0);
        }
        __syncthreads();
    }
    float gb = gbp[0];
    long tbase = (long)t * N_ * N_;
    int row0 = blockIdx.y * 128, col0 = blockIdx.x * 128;
    #pragma unroll
    for (int fm = 0; fm < 4; ++fm) {
        int er = row0 + wr * 64 + fm * 16 + (l >> 4) * 4;
        #pragma unroll
        for (int fn = 0; fn < 4; ++fn) {
            int ec = col0 + wc * 64 + fn * 16 + (l & 15);
            #pragma unroll
            for (int rg = 0; rg < 4; ++rg) {
                float zz = acc[fm][fn][rg] + gb;   // q pre-scaled by 1/16
                long idx = tbase + (long)(er + rg) * N_ + ec;
                __builtin_nontemporal_store(zz, &logits[idx]);
                __builtin_nontemporal_store(1.0f / (1.0f + __expf(-zz)), &probs[idx]);
            }
        }
    }
}

// ---------------- 64x64 guarded MFMA GEMM (N=48 DBC) -------------------------
__global__ __launch_bounds__(256) void mfma_gemm64(
    const bf16* __restrict__ A, int lda,
    const bf16* __restrict__ BT, int ldbt,
    float* __restrict__ Cf, int ldc,
    int M, int N, int K, const float* __restrict__ bias)
{
    __shared__ short As[64][40];
    __shared__ short Bs[64][40];
    int tid = threadIdx.x;
    int w = tid >> 6, l = tid & 63;
    int row0 = blockIdx.y * 64, col0 = blockIdx.x * 64;
    int sr = tid >> 2, sk = (tid & 3) * 8;
    const short* Ag = (const short*)A;
    const short* Bg = (const short*)BT;
    f32x4 acc[4] = {};
    for (int k0 = 0; k0 < K; k0 += 32) {
        *(s16x8*)&As[sr][sk] = *(const s16x8*)(Ag + (long)(row0 + sr) * lda + k0 + sk);
        int bn = col0 + sr;
        s16x8 bv = {};
        if (bn < N) bv = *(const s16x8*)(Bg + (long)bn * ldbt + k0 + sk);
        *(s16x8*)&Bs[sr][sk] = bv;
        __syncthreads();
        s16x8 a = *(const s16x8*)&As[w * 16 + (l & 15)][(l >> 4) * 8];
        #pragma unroll
        for (int ct = 0; ct < 4; ++ct) {
            s16x8 b = *(const s16x8*)&Bs[ct * 16 + (l & 15)][(l >> 4) * 8];
            acc[ct] = __builtin_amdgcn_mfma_f32_16x16x32_bf16(a, b, acc[ct], 0, 0, 0);
        }
        __syncthreads();
    }
    int er = row0 + w * 16 + (l >> 4) * 4;
    int ec = l & 15;
    #pragma unroll
    for (int ct = 0; ct < 4; ++ct) {
        int gc = col0 + ct * 16 + ec;
        if (gc >= N) continue;
        float bb = bias ? bias[gc] : 0.0f;
        #pragma unroll
        for (int rg = 0; rg < 4; ++rg)
            Cf[(long)(er + rg) * ldc + gc] = acc[ct][rg] + bb;
    }
}

// ---------------- gather aggregation, 4-deep unrolled ------------------------
__global__ __launch_bounds__(256) void agg_gather(
    const unsigned short* __restrict__ IDX, const int* __restrict__ CNT,
    const bf16* __restrict__ Bm, long tstride,
    bf16* __restrict__ out, int old, int ooff)
{
    int r = blockIdx.x;
    int t = r >> 10;
    const bf16* B = Bm + (long)t * tstride;
    __shared__ unsigned short sidx[128];
    int tid = threadIdx.x;
    int cnt = CNT[r];
    if (tid < 128) sidx[tid] = IDX[(long)r * 128 + tid];
    __syncthreads();
    float a0 = 0.0f, a1 = 0.0f, a2 = 0.0f, a3 = 0.0f;
    int k = 0;
    for (; k + 4 <= cnt; k += 4) {
        float v0 = b2f(B[(long)sidx[k]     * 256 + tid]);
        float v1 = b2f(B[(long)sidx[k + 1] * 256 + tid]);
        float v2 = b2f(B[(long)sidx[k + 2] * 256 + tid]);
        float v3 = b2f(B[(long)sidx[k + 3] * 256 + tid]);
        a0 += v0; a1 += v1; a2 += v2; a3 += v3;
    }
    for (; k < cnt; ++k) a0 += b2f(B[(long)sidx[k] * 256 + tid]);
    out[(long)r * old + ooff + tid] = f2b((a0 + a1) + (a2 + a3));
}

// ---------------- row LayerNorm (ln1), bf16 input ----------------------------
__global__ __launch_bounds__(256) void row_ln1(
    const bf16* __restrict__ in, const float* __restrict__ addf,
    const float* __restrict__ g, const float* __restrict__ b,
    bf16* __restrict__ out, int rows)
{
    int wv = threadIdx.x >> 6, lane = threadIdx.x & 63;
    int row = blockIdx.x * 4 + wv;
    if (row >= rows) return;
    const bf16* p = in + (long)row * 256 + lane * 4;
    const float* q = addf + (long)(row & 1023) * 256 + lane * 4;
    float v[4];
    #pragma unroll
    for (int u = 0; u < 4; ++u) v[u] = fmaxf(b2f(p[u]) + q[u], 0.0f);
    float s = v[0] + v[1] + v[2] + v[3];
    #pragma unroll
    for (int o = 32; o >= 1; o >>= 1) s += __shfl_xor(s, o, 64);
    float mu = s * (1.0f / 256.0f);
    float d0 = v[0]-mu, d1 = v[1]-mu, d2 = v[2]-mu, d3 = v[3]-mu;
    float sq = d0*d0 + d1*d1 + d2*d2 + d3*d3;
    #pragma unroll
    for (int o = 32; o >= 1; o >>= 1) sq += __shfl_xor(sq, o, 64);
    float rs = rsqrtf(sq * (1.0f / 256.0f) + 1e-5f);
    bf16* o = out + (long)row * 512 + lane * 4;
    #pragma unroll
    for (int u = 0; u < 4; ++u)
        o[u] = f2b((v[u] - mu) * rs * g[lane * 4 + u] + b[lane * 4 + u]);
}

// ---------------- fused double LayerNorm (bf16 in): ln2->X2b ; mb_ln->XNb ----
__global__ __launch_bounds__(256) void dbl_ln(
    const bf16* __restrict__ in,
    const float* __restrict__ g2, const float* __restrict__ b2,
    const float* __restrict__ gm, const float* __restrict__ bm,
    bf16* __restrict__ X2b, bf16* __restrict__ XNb, int rows)
{
    int wv = threadIdx.x >> 6, lane = threadIdx.x & 63;
    int row = blockIdx.x * 4 + wv;
    if (row >= rows) return;
    const bf16* p = in + (long)row * 256 + lane * 4;
    float v[4];
    #pragma unroll
    for (int u = 0; u < 4; ++u) v[u] = fmaxf(b2f(p[u]), 0.0f);
    float s = v[0] + v[1] + v[2] + v[3];
    #pragma unroll
    for (int o = 32; o >= 1; o >>= 1) s += __shfl_xor(s, o, 64);
    float mu = s * (1.0f / 256.0f);
    float sq = 0.0f;
    #pragma unroll
    for (int u = 0; u < 4; ++u) { float d = v[u] - mu; sq += d * d; }
    #pragma unroll
    for (int o = 32; o >= 1; o >>= 1) sq += __shfl_xor(sq, o, 64);
    float rs = rsqrtf(sq * (1.0f / 256.0f) + 1e-5f);
    float o1[4];
    bf16* qx = X2b + (long)row * 256 + lane * 4;
    #pragma unroll
    for (int u = 0; u < 4; ++u) {
        o1[u] = (v[u] - mu) * rs * g2[lane * 4 + u] + b2[lane * 4 + u];
        qx[u] = f2b(o1[u]);
    }
    float s2 = o1[0] + o1[1] + o1[2] + o1[3];
    #pragma unroll
    for (int o = 32; o >= 1; o >>= 1) s2 += __shfl_xor(s2, o, 64);
    float mu2 = s2 * (1.0f / 256.0f);
    float sq2 = 0.0f;
    #pragma unroll
    for (int u = 0; u < 4; ++u) { float d = o1[u] - mu2; sq2 += d * d; }
    #pragma unroll
    for (int o = 32; o >= 1; o >>= 1) sq2 += __shfl_xor(sq2, o, 64);
    float rs2 = rsqrtf(sq2 * (1.0f / 256.0f) + 1e-5f);
    bf16* qn = XNb + (long)row * 256 + lane * 4;
    #pragma unroll
    for (int u = 0; u < 4; ++u)
        qn[u] = f2b((o1[u] - mu2) * rs2 * gm[lane * 4 + u] + bm[lane * 4 + u]);
}

// ---------------- barrier-free scan with fused delta + prefetch --------------
__global__ __launch_bounds__(512) void scan2(
    const bf16* __restrict__ X1,
    bf16* __restrict__ G,
    const float* __restrict__ DBC,
    const bf16* __restrict__ DTwT,
    const float* __restrict__ DTb,
    const float* __restrict__ A_log,
    const float* __restrict__ D_vec)
{
    int n = blockIdx.x;
    int e = threadIdx.x;
    float A[SD_], wdt[SD_];
    #pragma unroll
    for (int s = 0; s < SD_; ++s) A[s] = -__expf(A_log[e * SD_ + s]);
    #pragma unroll
    for (int s = 0; s < SD_; ++s) wdt[s] = b2f(DTwT[e * SD_ + s]);
    float dtb = DTb[e];
    float Dv = D_vec[e];
    float h[SD_];
    #pragma unroll
    for (int s = 0; s < SD_; ++s) h[s] = 0.0f;
    long rowe = (long)n * E_ + e;
    float x1v = b2f(X1[rowe]);
    float gvv = b2f(G[rowe]);
    for (int t = 0; t < T_; ++t) {
        long row = (long)t * N_ + n;
        // prefetch next-t activations before the serial exp chain
        float x1n = 0.0f, gvn = 0.0f;
        if (t + 1 < T_) {
            long rn = row * (long)E_ + (long)N_ * E_ + e;
            x1n = b2f(X1[rn]);
            gvn = b2f(G[rn]);
        }
        const float* dbc = DBC + row * 48;
        float z = dtb;
        #pragma unroll
        for (int k = 0; k < SD_; ++k) z += dbc[k] * wdt[k];
        float dt = (z > 15.0f) ? z : __logf(1.0f + __expf(z));
        float dx = dt * x1v;
        float yv = 0.0f;
        #pragma unroll
        for (int s = 0; s < SD_; ++s) {
            h[s] = __expf(dt * A[s]) * h[s] + dx * dbc[16 + s];
            yv += dbc[32 + s] * h[s];
        }
        G[row * (long)E_ + e] = f2b((yv + x1v * Dv) * gvv);
        x1v = x1n; gvv = gvn;
    }
}

// =============================================================================
extern "C" void kernel_launch(void* const* d_in, const int* in_sizes, int n_in,
                              void* d_out, int out_size, void* d_ws, size_t ws_size,
                              hipStream_t stream)
{
    if (ws_size < (size_t)(212 * MBYTE)) return;
    if (n_in != 32 || in_sizes[0] != T_ * N_ * N_ || in_sizes[15] != 256 * 1024) return;

    const float* adj = (const float*)d_in[0];
    const float* P1w = (const float*)d_in[1];
    const float* P1b = (const float*)d_in[2];
    const float* U1w = (const float*)d_in[3];
    const float* U1b = (const float*)d_in[4];
    const float* L1g = (const float*)d_in[5];
    const float* L1b = (const float*)d_in[6];
    const float* P2w = (const float*)d_in[7];
    const float* P2b = (const float*)d_in[8];
    const float* U2w = (const float*)d_in[9];
    const float* U2b = (const float*)d_in[10];
    const float* L2g = (const float*)d_in[11];
    const float* L2b = (const float*)d_in[12];
    const float* MBg = (const float*)d_in[13];
    const float* MBb = (const float*)d_in[14];
    const float* INw = (const float*)d_in[15];
    const float* INb = (const float*)d_in[16];
    const float* DLw = (const float*)d_in[17];
    const float* DLb = (const float*)d_in[18];
    const float* DTw = (const float*)d_in[19];
    const float* DTb = (const float*)d_in[20];
    const float* BPw = (const float*)d_in[21];
    const float* BPb = (const float*)d_in[22];
    const float* CPw = (const float*)d_in[23];
    const float* CPb = (const float*)d_in[24];
    const float* ALg = (const float*)d_in[25];
    const float* DV  = (const float*)d_in[26];
    const float* OWw = (const float*)d_in[27];
    const float* OWb = (const float*)d_in[28];
    const float* QWw = (const float*)d_in[29];
    const float* KWw = (const float*)d_in[30];
    const float* GB  = (const float*)d_in[31];

    char* w = (char*)d_ws;
    bf16*  XPREb = (bf16*)(w + 0);                   // [32768,256] bf16 pre-LN scratch
    bf16*  XCATb = (bf16*)(w + 32 * MBYTE);          // [32768,512] x|agg2
    bf16*  AGG1b = (bf16*)(w + 64 * MBYTE);          // [32768,256]; later M2b, OUTb
    bf16*  M2b   = (bf16*)(w + 64 * MBYTE);
    bf16*  OUTb  = (bf16*)(w + 64 * MBYTE);
    bf16*  X1b   = (bf16*)(w + 80 * MBYTE);          // [32768,512]
    bf16*  Gb    = (bf16*)(w + 112 * MBYTE);         // [32768,512] gate -> Y
    bf16*  X2b   = (bf16*)(w + 144 * MBYTE);         // [32768,256] bf16 residual
    bf16*  Qb    = (bf16*)(w + 144 * MBYTE);         // over dead X2b
    bf16*  Kb    = (bf16*)(w + 160 * MBYTE);
    bf16*  XNb   = (bf16*)(w + 176 * MBYTE);         // [32768,256]
    float* DBC   = (float*)(w + 192 * MBYTE);        // [32768,48] f32
    unsigned short* IDX = (unsigned short*)(w + 198 * MBYTE);  // [32768][128]
    int*   CNT   = (int*)(w + 206 * MBYTE);
    float* BASE1 = (float*)(w + 207 * MBYTE);        // [1024,256] f32
    bf16*  PEb   = (bf16*)(w + 208 * MBYTE);
    bf16*  M1b   = (bf16*)(w + 208 * MBYTE + 524288);
    bf16*  WT    = (bf16*)(w + 209 * MBYTE);
    float* B48   = (float*)(w + 211 * MBYTE);

    bf16* P1wT  = WT + 0;
    bf16* U1wT  = WT + 65536;
    bf16* P2wT  = WT + 196608;
    bf16* U2wT  = WT + 262144;
    bf16* INwT  = WT + 393216;
    bf16* DTwT  = WT + 655360;
    bf16* OWwT  = WT + 663552;
    bf16* QWwT  = WT + 794624;
    bf16* KWwT  = WT + 860160;
    bf16* DBCwT = WT + 925696;

    float* out0       = (float*)d_out;
    float* out_probs  = out0 + (long)T_ * N_ * H_;
    float* out_logits = out_probs + (long)T_ * N_ * N_;

    const int RN = T_ * N_;
    dim3 blk(256);
    const float* fnull = nullptr;
    float* f32null = nullptr;
    bf16*  b16null = nullptr;
    const bf16* cb16null = nullptr;

    // ---- prep: pe + 13 transposes + pack48 + idx_build in ONE launch ----
    PrepArgs P;
    P.t[0]  = {P1w, 256, 256,  P1wT, 256, 1.0f};
    P.t[1]  = {U1w, 512, 256,  U1wT, 512, 1.0f};
    P.t[2]  = {P2w, 256, 256,  P2wT, 256, 1.0f};
    P.t[3]  = {U2w, 512, 256,  U2wT, 512, 1.0f};
    P.t[4]  = {INw, 256, 1024, INwT, 256, 1.0f};
    P.t[5]  = {DTw, 16,  512,  DTwT, 16, 1.0f};
    P.t[6]  = {OWw, 512, 256,  OWwT, 512, 1.0f};
    P.t[7]  = {QWw, 256, 256,  QWwT, 256, 0.0625f};   // fold score scale into q
    P.t[8]  = {KWw, 256, 256,  KWwT, 256, 1.0f};
    P.t[9]  = {DLw, 512, 16,   DBCwT, 512, 1.0f};
    P.t[10] = {BPw, 512, 16,   DBCwT + 16 * 512, 512, 1.0f};
    P.t[11] = {CPw, 512, 16,   DBCwT + 32 * 512, 512, 1.0f};
    P.t[12] = {DLw, 1,   1,    DBCwT, 512, 1.0f};     // dummy
    P.pe = PEb; P.pa = DLb; P.pb = BPb; P.pc = CPb; P.po = B48;
    P.adj = adj; P.IDX = IDX; P.CNT = CNT;
    hipLaunchKernelGGL(prep_kernel, dim3(32, 32, 47), blk, 0, stream, P);

    // ---- m1 (z0) ; base1 (z1) ----
    hipLaunchKernelGGL((mfma_gemm128<0, false>), dim3(2, 8, 2), blk, 0, stream,
                       PEb, 256, P1wT, U1wT, 256, 512,
                       f32null, BASE1, M1b, b16null, 256, 256, P1b, U1b, cb16null);

    // ---- agg1 ----
    hipLaunchKernelGGL(agg_gather, dim3(RN), blk, 0, stream, IDX, CNT, M1b, 0L, AGG1b, 256, 0);

    // ---- x-pre = agg1 @ U1[256:] (bf16) ; ln1 -> XCAT[:, :256] ----
    hipLaunchKernelGGL((mfma_gemm128<0, false>), dim3(2, 256, 1), blk, 0, stream,
                       AGG1b, 256, U1wT + 256, U1wT + 256, 512, 512,
                       f32null, f32null, XPREb, b16null, 256, 256, fnull, fnull, cb16null);
    hipLaunchKernelGGL(row_ln1, dim3(RN / 4), blk, 0, stream, XPREb, BASE1, L1g, L1b, XCATb, RN);

    // ---- m2 ----
    hipLaunchKernelGGL((mfma_gemm128<0, false>), dim3(2, 256, 1), blk, 0, stream,
                       XCATb, 512, P2wT, P2wT, 256, 256,
                       f32null, f32null, M2b, b16null, 256, 256, P2b, fnull, cb16null);

    // ---- agg2 -> XCAT[:, 256:512] ----
    hipLaunchKernelGGL(agg_gather, dim3(RN), blk, 0, stream, IDX, CNT, M2b,
                       (long)N_ * 256, XCATb, 512, 256);

    // ---- x2-pre = [x|agg2] @ U2 + U2b (bf16) ; dbl_ln -> X2b, XNb ----
    hipLaunchKernelGGL((mfma_gemm128<0, false>), dim3(2, 256, 1), blk, 0, stream,
                       XCATb, 512, U2wT, U2wT, 512, 512,
                       f32null, f32null, XPREb, b16null, 256, 512, U2b, fnull, cb16null);
    hipLaunchKernelGGL(dbl_ln, dim3(RN / 4), blk, 0, stream,
                       XPREb, L2g, L2b, MBg, MBb, X2b, XNb, RN);

    // ---- x1 (z0) ; gate (z1), fused silu ----
    hipLaunchKernelGGL((mfma_gemm128<1, false>), dim3(4, 256, 2), blk, 0, stream,
                       XNb, 256, INwT, INwT + 512 * 256, 256, 256,
                       f32null, f32null, X1b, Gb, 512, 256, INb, INb + 512, cb16null);

    // ---- [d1|B|C] = x1 @ [dw|bw|cw] + b48 ----
    hipLaunchKernelGGL(mfma_gemm64, dim3(1, 512), blk, 0, stream,
                       X1b, 512, DBCwT, 512, DBC, 48, RN, 48, 512, B48);

    // ---- barrier-free scan with fused delta (Y overwrites Gb) ----
    hipLaunchKernelGGL(scan2, dim3(N_), dim3(512), 0, stream,
                       X1b, Gb, DBC, DTwT, DTb, ALg, DV);

    // ---- outs = y @ out_w + out_b + x2 -> out0 (f32, NT) + OUTb (bf16) ----
    hipLaunchKernelGGL((mfma_gemm128<0, true>), dim3(2, 256, 1), blk, 0, stream,
                       Gb, 512, OWwT, OWwT, 512, 512,
                       out0, f32null, OUTb, b16null, 256, 512, OWb, fnull, X2b);

    // ---- q (z0, pre-scaled), k (z1) ----
    hipLaunchKernelGGL((mfma_gemm128<0, false>), dim3(2, 256, 2), blk, 0, stream,
                       OUTb, 256, QWwT, KWwT, 256, 256,
                       f32null, f32null, Qb, Kb, 256, 256, fnull, fnull, cb16null);

    // ---- logits/probs ----
    hipLaunchKernelGGL(score_mfma128, dim3(8, 8, T_), blk, 0, stream,
                       Qb, Kb, out_probs, out_logits, GB);
}

// Round 16
// 552.856 us; speedup vs baseline: 1.0092x; 1.0092x over previous
//
#include <hip/hip_runtime.h>
#include <hip/hip_bf16.h>

typedef __hip_bfloat16 bf16;
typedef short s16x8 __attribute__((ext_vector_type(8)));
typedef float f32x4 __attribute__((ext_vector_type(4)));

#define T_  32
#define N_  1024
#define H_  256
#define E_  512
#define SD_ 16

static const long MBYTE = 1024L * 1024L;

__device__ __forceinline__ float b2f(bf16 v){ return __bfloat162float(v); }
__device__ __forceinline__ bf16  f2b(float v){ return __float2bfloat16(v); }

// direct global->LDS 16B async copy (dest = wave-uniform base + lane*16)
#define G2L16(gp, lp) __builtin_amdgcn_global_load_lds( \
    (const __attribute__((address_space(1))) void*)(const void*)(gp), \
    (__attribute__((address_space(3))) void*)(void*)(lp), 16, 0, 0)

// ---------------- fused prep: 13 transposes + pe + pack48 + idx_build ---------
struct TDesc { const float* src; int K; int N; bf16* dst; int ldT; float scale; };
struct PrepArgs {
    TDesc t[13];
    bf16* pe;
    const float* pa; const float* pb; const float* pc; float* po;
    const float* adj; unsigned short* IDX; int* CNT;
};

__global__ __launch_bounds__(256) void prep_kernel(PrepArgs P){
    int z = blockIdx.z;
    int tid = threadIdx.x;
    if (z < 13) {
        const TDesc d = P.t[z];
        int k0 = blockIdx.x * 32, n0 = blockIdx.y * 32;
        if (k0 >= d.K || n0 >= d.N) return;
        __shared__ float S[32][33];
        int r = tid >> 3, c4 = (tid & 7) * 4;
        #pragma unroll
        for (int u = 0; u < 4; ++u) {
            int k = k0 + r, n = n0 + c4 + u;
            S[r][c4 + u] = (k < d.K && n < d.N) ? d.src[(long)k * d.N + n] : 0.0f;
        }
        __syncthreads();
        int n = n0 + (tid >> 3);
        #pragma unroll
        for (int u = 0; u < 4; ++u) {
            int k = k0 + (tid & 7) * 4 + u;
            if (n < d.N && k < d.K)
                d.dst[(long)n * d.ldT + k] = f2b(S[(tid & 7) * 4 + u][tid >> 3] * d.scale);
        }
    } else if (z == 13) {
        int n = blockIdx.y * 32 + blockIdx.x;   // 0..1023
        int dd = tid;
        int i2 = (dd >> 1) * 2;
        float div = __expf((float)i2 * (-9.210340371976184f / 256.0f));
        float ang = (float)n * div;
        P.pe[n * 256 + dd] = f2b((dd & 1) ? __cosf(ang) : __sinf(ang));
    } else if (z == 14) {
        if (blockIdx.x || blockIdx.y) return;
        if (tid < 16) P.po[tid] = P.pa[tid];
        else if (tid < 32) P.po[tid] = P.pb[tid - 16];
        else if (tid < 48) P.po[tid] = P.pc[tid - 32];
    } else {
        int r = (z - 15) * 1024 + blockIdx.y * 32 + blockIdx.x;
        const float* arow = P.adj + ((long)r << 10);
        __shared__ int wcnt[4];
        int wv = tid >> 6, lane = tid & 63;
        int total = 0;
        unsigned short* out = P.IDX + (long)r * 128;
        #pragma unroll
        for (int u = 0; u < 4; ++u) {
            float av = arow[u * 256 + tid];
            unsigned long long mask = __ballot(av != 0.0f);
            if (lane == 0) wcnt[wv] = __popcll(mask);
            __syncthreads();
            int base = total;
            for (int w2 = 0; w2 < wv; ++w2) base += wcnt[w2];
            if (av != 0.0f) {
                int pos = base + __popcll(mask & ((1ull << lane) - 1ull));
                if (pos < 128) out[pos] = (unsigned short)(u * 256 + tid);
            }
            total += wcnt[0] + wcnt[1] + wcnt[2] + wcnt[3];
            __syncthreads();
        }
        if (tid == 0) P.CNT[r] = total < 128 ? total : 128;
    }
}

// ---------------- 128x128 MFMA GEMM, BK=64, swizzled LDS, z-dual -------------
// LDS layout: [128][64] shorts; slot (r,c') holds global 16B-chunk c'^(r&7).
// Staged via global_load_lds with inverse-swizzled per-lane SOURCE (rule #21).
template<int OP, bool NTF>
__global__ __launch_bounds__(256) void mfma_gemm128(
    const bf16* __restrict__ A, int lda,
    const bf16* BT0, const bf16* BT1, int ldbt0, int ldbt1,
    float* Cf0, float* Cf1, bf16* Cb0, bf16* Cb1, int ldc,
    int K, const float* bias0, const float* bias1, const bf16* resb)
{
    int z = blockIdx.z;
    const bf16* BT = z ? BT1 : BT0;
    int ldbt = z ? ldbt1 : ldbt0;
    float* Cf = z ? Cf1 : Cf0;
    bf16*  Cb = z ? Cb1 : Cb0;
    const float* bias = z ? bias1 : bias0;

    __shared__ short As[8192];
    __shared__ short Bs[8192];
    int tid = threadIdx.x;
    int w = tid >> 6, l = tid & 63;
    int wr = w >> 1, wc = w & 1;
    long row0 = (long)blockIdx.y * 128, col0 = (long)blockIdx.x * 128;
    const short* Ag = (const short*)A + row0 * lda;
    const short* Bg = (const short*)BT + col0 * ldbt;
    int strow = w * 8 + (l >> 3);                 // +i*32
    int stcol = ((l & 7) ^ (l >> 3)) * 8;         // inverse-swizzled source chunk
    short* lA = As + w * 512 + l * 8;             // +i*2048
    short* lB = Bs + w * 512 + l * 8;
    f32x4 acc[4][4] = {};
    for (int k0 = 0; k0 < K; k0 += 64) {
        #pragma unroll
        for (int i = 0; i < 4; ++i) {
            G2L16(Ag + (long)(strow + i * 32) * lda + k0 + stcol, lA + i * 2048);
            G2L16(Bg + (long)(strow + i * 32) * ldbt + k0 + stcol, lB + i * 2048);
        }
        __syncthreads();
        #pragma unroll
        for (int kk = 0; kk < 2; ++kk) {
            s16x8 af[4], bf[4];
            #pragma unroll
            for (int f = 0; f < 4; ++f) {
                int Ra = wr * 64 + f * 16 + (l & 15);
                af[f] = *(const s16x8*)&As[Ra * 64 + (((kk * 4 + (l >> 4)) ^ (Ra & 7)) * 8)];
                int Rb = wc * 64 + f * 16 + (l & 15);
                bf[f] = *(const s16x8*)&Bs[Rb * 64 + (((kk * 4 + (l >> 4)) ^ (Rb & 7)) * 8)];
            }
            #pragma unroll
            for (int fm = 0; fm < 4; ++fm)
                #pragma unroll
                for (int fn = 0; fn < 4; ++fn)
                    acc[fm][fn] = __builtin_amdgcn_mfma_f32_16x16x32_bf16(af[fm], bf[fn], acc[fm][fn], 0, 0, 0);
        }
        __syncthreads();
    }
    #pragma unroll
    for (int fm = 0; fm < 4; ++fm) {
        int er = (int)row0 + wr * 64 + fm * 16 + (l >> 4) * 4;
        #pragma unroll
        for (int fn = 0; fn < 4; ++fn) {
            int ec = (int)col0 + wc * 64 + fn * 16 + (l & 15);
            float bb = bias ? bias[ec] : 0.0f;
            #pragma unroll
            for (int rg = 0; rg < 4; ++rg) {
                long idx = (long)(er + rg) * ldc + ec;
                float v = acc[fm][fn][rg] + bb;
                if (resb) v += b2f(resb[idx]);
                if (OP == 1) v = v / (1.0f + __expf(-v));
                if (Cf) { if (NTF) __builtin_nontemporal_store(v, &Cf[idx]); else Cf[idx] = v; }
                if (Cb) Cb[idx] = f2b(v);
            }
        }
    }
}

// ---------------- 128x128 MFMA score, BK=64 swizzled (q pre-scaled 1/16) -----
__global__ __launch_bounds__(256) void score_mfma128(
    const bf16* __restrict__ Q, const bf16* __restrict__ Km,
    float* __restrict__ probs, float* __restrict__ logits,
    const float* __restrict__ gbp)
{
    int t = blockIdx.z;
    const short* Ag = (const short*)(Q  + (long)t * N_ * 256) + (long)blockIdx.y * 128 * 256;
    const short* Bg = (const short*)(Km + (long)t * N_ * 256) + (long)blockIdx.x * 128 * 256;
    __shared__ short As[8192];
    __shared__ short Bs[8192];
    int tid = threadIdx.x;
    int w = tid >> 6, l = tid & 63;
    int wr = w >> 1, wc = w & 1;
    int strow = w * 8 + (l >> 3);
    int stcol = ((l & 7) ^ (l >> 3)) * 8;
    short* lA = As + w * 512 + l * 8;
    short* lB = Bs + w * 512 + l * 8;
    f32x4 acc[4][4] = {};
    for (int k0 = 0; k0 < 256; k0 += 64) {
        #pragma unroll
        for (int i = 0; i < 4; ++i) {
            G2L16(Ag + (long)(strow + i * 32) * 256 + k0 + stcol, lA + i * 2048);
            G2L16(Bg + (long)(strow + i * 32) * 256 + k0 + stcol, lB + i * 2048);
        }
        __syncthreads();
        #pragma unroll
        for (int kk = 0; kk < 2; ++kk) {
            s16x8 af[4], bf[4];
            #pragma unroll
            for (int f = 0; f < 4; ++f) {
                int Ra = wr * 64 + f * 16 + (l & 15);
                af[f] = *(const s16x8*)&As[Ra * 64 + (((kk * 4 + (l >> 4)) ^ (Ra & 7)) * 8)];
                int Rb = wc * 64 + f * 16 + (l & 15);
                bf[f] = *(const s16x8*)&Bs[Rb * 64 + (((kk * 4 + (l >> 4)) ^ (Rb & 7)) * 8)];
            }
            #pragma unroll
            for (int fm = 0; fm < 4; ++fm)
                #pragma unroll
                for (int fn = 0; fn < 4; ++fn)
                    acc[fm][fn] = __builtin_amdgcn_mfma_f32_16x16x32_bf16(af[fm], bf[fn], acc[fm][fn], 0, 0, 0);
        }
        __syncthreads();
    }
    float gb = gbp[0];
    long tbase = (long)t * N_ * N_;
    int row0 = blockIdx.y * 128, col0 = blockIdx.x * 128;
    #pragma unroll
    for (int fm = 0; fm < 4; ++fm) {
        int er = row0 + wr * 64 + fm * 16 + (l >> 4) * 4;
        #pragma unroll
        for (int fn = 0; fn < 4; ++fn) {
            int ec = col0 + wc * 64 + fn * 16 + (l & 15);
            #pragma unroll
            for (int rg = 0; rg < 4; ++rg) {
                float zz = acc[fm][fn][rg] + gb;   // q pre-scaled by 1/16
                long idx = tbase + (long)(er + rg) * N_ + ec;
                __builtin_nontemporal_store(zz, &logits[idx]);
                __builtin_nontemporal_store(1.0f / (1.0f + __expf(-zz)), &probs[idx]);
            }
        }
    }
}

// ---------------- 64x64 guarded MFMA GEMM (N=48 DBC) -------------------------
__global__ __launch_bounds__(256) void mfma_gemm64(
    const bf16* __restrict__ A, int lda,
    const bf16* __restrict__ BT, int ldbt,
    float* __restrict__ Cf, int ldc,
    int M, int N, int K, const float* __restrict__ bias)
{
    __shared__ short As[64][40];
    __shared__ short Bs[64][40];
    int tid = threadIdx.x;
    int w = tid >> 6, l = tid & 63;
    int row0 = blockIdx.y * 64, col0 = blockIdx.x * 64;
    int sr = tid >> 2, sk = (tid & 3) * 8;
    const short* Ag = (const short*)A;
    const short* Bg = (const short*)BT;
    f32x4 acc[4] = {};
    for (int k0 = 0; k0 < K; k0 += 32) {
        *(s16x8*)&As[sr][sk] = *(const s16x8*)(Ag + (long)(row0 + sr) * lda + k0 + sk);
        int bn = col0 + sr;
        s16x8 bv = {};
        if (bn < N) bv = *(const s16x8*)(Bg + (long)bn * ldbt + k0 + sk);
        *(s16x8*)&Bs[sr][sk] = bv;
        __syncthreads();
        s16x8 a = *(const s16x8*)&As[w * 16 + (l & 15)][(l >> 4) * 8];
        #pragma unroll
        for (int ct = 0; ct < 4; ++ct) {
            s16x8 b = *(const s16x8*)&Bs[ct * 16 + (l & 15)][(l >> 4) * 8];
            acc[ct] = __builtin_amdgcn_mfma_f32_16x16x32_bf16(a, b, acc[ct], 0, 0, 0);
        }
        __syncthreads();
    }
    int er = row0 + w * 16 + (l >> 4) * 4;
    int ec = l & 15;
    #pragma unroll
    for (int ct = 0; ct < 4; ++ct) {
        int gc = col0 + ct * 16 + ec;
        if (gc >= N) continue;
        float bb = bias ? bias[gc] : 0.0f;
        #pragma unroll
        for (int rg = 0; rg < 4; ++rg)
            Cf[(long)(er + rg) * ldc + gc] = acc[ct][rg] + bb;
    }
}

// ---------------- gather aggregation, 4-deep unrolled ------------------------
__global__ __launch_bounds__(256) void agg_gather(
    const unsigned short* __restrict__ IDX, const int* __restrict__ CNT,
    const bf16* __restrict__ Bm, long tstride,
    bf16* __restrict__ out, int old, int ooff)
{
    int r = blockIdx.x;
    int t = r >> 10;
    const bf16* B = Bm + (long)t * tstride;
    __shared__ unsigned short sidx[128];
    int tid = threadIdx.x;
    int cnt = CNT[r];
    if (tid < 128) sidx[tid] = IDX[(long)r * 128 + tid];
    __syncthreads();
    float a0 = 0.0f, a1 = 0.0f, a2 = 0.0f, a3 = 0.0f;
    int k = 0;
    for (; k + 4 <= cnt; k += 4) {
        float v0 = b2f(B[(long)sidx[k]     * 256 + tid]);
        float v1 = b2f(B[(long)sidx[k + 1] * 256 + tid]);
        float v2 = b2f(B[(long)sidx[k + 2] * 256 + tid]);
        float v3 = b2f(B[(long)sidx[k + 3] * 256 + tid]);
        a0 += v0; a1 += v1; a2 += v2; a3 += v3;
    }
    for (; k < cnt; ++k) a0 += b2f(B[(long)sidx[k] * 256 + tid]);
    out[(long)r * old + ooff + tid] = f2b((a0 + a1) + (a2 + a3));
}

// ---------------- row LayerNorm (ln1) ----------------------------------------
__global__ __launch_bounds__(256) void row_ln1(
    const float* __restrict__ in, const float* __restrict__ addf,
    const float* __restrict__ g, const float* __restrict__ b,
    bf16* __restrict__ out, int rows)
{
    int wv = threadIdx.x >> 6, lane = threadIdx.x & 63;
    int row = blockIdx.x * 4 + wv;
    if (row >= rows) return;
    const float* p = in + (long)row * 256 + lane * 4;
    const float* q = addf + (long)(row & 1023) * 256 + lane * 4;
    float v[4];
    #pragma unroll
    for (int u = 0; u < 4; ++u) v[u] = fmaxf(p[u] + q[u], 0.0f);
    float s = v[0] + v[1] + v[2] + v[3];
    #pragma unroll
    for (int o = 32; o >= 1; o >>= 1) s += __shfl_xor(s, o, 64);
    float mu = s * (1.0f / 256.0f);
    float d0 = v[0]-mu, d1 = v[1]-mu, d2 = v[2]-mu, d3 = v[3]-mu;
    float sq = d0*d0 + d1*d1 + d2*d2 + d3*d3;
    #pragma unroll
    for (int o = 32; o >= 1; o >>= 1) sq += __shfl_xor(sq, o, 64);
    float rs = rsqrtf(sq * (1.0f / 256.0f) + 1e-5f);
    bf16* o = out + (long)row * 512 + lane * 4;
    #pragma unroll
    for (int u = 0; u < 4; ++u)
        o[u] = f2b((v[u] - mu) * rs * g[lane * 4 + u] + b[lane * 4 + u]);
}

// ---------------- fused double LayerNorm: relu->ln2->X2b(bf16) ; mb_ln->XNb --
__global__ __launch_bounds__(256) void dbl_ln(
    const float* __restrict__ in,
    const float* __restrict__ g2, const float* __restrict__ b2,
    const float* __restrict__ gm, const float* __restrict__ bm,
    bf16* __restrict__ X2b, bf16* __restrict__ XNb, int rows)
{
    int wv = threadIdx.x >> 6, lane = threadIdx.x & 63;
    int row = blockIdx.x * 4 + wv;
    if (row >= rows) return;
    const float* p = in + (long)row * 256 + lane * 4;
    float v[4];
    #pragma unroll
    for (int u = 0; u < 4; ++u) v[u] = fmaxf(p[u], 0.0f);
    float s = v[0] + v[1] + v[2] + v[3];
    #pragma unroll
    for (int o = 32; o >= 1; o >>= 1) s += __shfl_xor(s, o, 64);
    float mu = s * (1.0f / 256.0f);
    float sq = 0.0f;
    #pragma unroll
    for (int u = 0; u < 4; ++u) { float d = v[u] - mu; sq += d * d; }
    #pragma unroll
    for (int o = 32; o >= 1; o >>= 1) sq += __shfl_xor(sq, o, 64);
    float rs = rsqrtf(sq * (1.0f / 256.0f) + 1e-5f);
    float o1[4];
    bf16* qx = X2b + (long)row * 256 + lane * 4;
    #pragma unroll
    for (int u = 0; u < 4; ++u) {
        o1[u] = (v[u] - mu) * rs * g2[lane * 4 + u] + b2[lane * 4 + u];
        qx[u] = f2b(o1[u]);
    }
    float s2 = o1[0] + o1[1] + o1[2] + o1[3];
    #pragma unroll
    for (int o = 32; o >= 1; o >>= 1) s2 += __shfl_xor(s2, o, 64);
    float mu2 = s2 * (1.0f / 256.0f);
    float sq2 = 0.0f;
    #pragma unroll
    for (int u = 0; u < 4; ++u) { float d = o1[u] - mu2; sq2 += d * d; }
    #pragma unroll
    for (int o = 32; o >= 1; o >>= 1) sq2 += __shfl_xor(sq2, o, 64);
    float rs2 = rsqrtf(sq2 * (1.0f / 256.0f) + 1e-5f);
    bf16* qn = XNb + (long)row * 256 + lane * 4;
    #pragma unroll
    for (int u = 0; u < 4; ++u)
        qn[u] = f2b((o1[u] - mu2) * rs2 * gm[lane * 4 + u] + bm[lane * 4 + u]);
}

// ---------------- barrier-free scan with fused delta -------------------------
__global__ __launch_bounds__(512) void scan2(
    const bf16* __restrict__ X1,
    bf16* __restrict__ G,
    const float* __restrict__ DBC,
    const bf16* __restrict__ DTwT,
    const float* __restrict__ DTb,
    const float* __restrict__ A_log,
    const float* __restrict__ D_vec)
{
    int n = blockIdx.x;
    int e = threadIdx.x;
    float A[SD_], wdt[SD_];
    #pragma unroll
    for (int s = 0; s < SD_; ++s) A[s] = -__expf(A_log[e * SD_ + s]);
    #pragma unroll
    for (int s = 0; s < SD_; ++s) wdt[s] = b2f(DTwT[e * SD_ + s]);
    float dtb = DTb[e];
    float Dv = D_vec[e];
    float h[SD_];
    #pragma unroll
    for (int s = 0; s < SD_; ++s) h[s] = 0.0f;
    for (int t = 0; t < T_; ++t) {
        long row = (long)t * N_ + n;
        const float* dbc = DBC + row * 48;
        float z = dtb;
        #pragma unroll
        for (int k = 0; k < SD_; ++k) z += dbc[k] * wdt[k];
        float dt = (z > 15.0f) ? z : __logf(1.0f + __expf(z));
        float x1 = b2f(X1[row * (long)E_ + e]);
        float gv = b2f(G[row * (long)E_ + e]);
        float dx = dt * x1;
        float yv = 0.0f;
        #pragma unroll
        for (int s = 0; s < SD_; ++s) {
            h[s] = __expf(dt * A[s]) * h[s] + dx * dbc[16 + s];
            yv += dbc[32 + s] * h[s];
        }
        G[row * (long)E_ + e] = f2b((yv + x1 * Dv) * gv);
    }
}

// =============================================================================
extern "C" void kernel_launch(void* const* d_in, const int* in_sizes, int n_in,
                              void* d_out, int out_size, void* d_ws, size_t ws_size,
                              hipStream_t stream)
{
    if (ws_size < (size_t)(212 * MBYTE)) return;
    if (n_in != 32 || in_sizes[0] != T_ * N_ * N_ || in_sizes[15] != 256 * 1024) return;

    const float* adj = (const float*)d_in[0];
    const float* P1w = (const float*)d_in[1];
    const float* P1b = (const float*)d_in[2];
    const float* U1w = (const float*)d_in[3];
    const float* U1b = (const float*)d_in[4];
    const float* L1g = (const float*)d_in[5];
    const float* L1b = (const float*)d_in[6];
    const float* P2w = (const float*)d_in[7];
    const float* P2b = (const float*)d_in[8];
    const float* U2w = (const float*)d_in[9];
    const float* U2b = (const float*)d_in[10];
    const float* L2g = (const float*)d_in[11];
    const float* L2b = (const float*)d_in[12];
    const float* MBg = (const float*)d_in[13];
    const float* MBb = (const float*)d_in[14];
    const float* INw = (const float*)d_in[15];
    const float* INb = (const float*)d_in[16];
    const float* DLw = (const float*)d_in[17];
    const float* DLb = (const float*)d_in[18];
    const float* DTw = (const float*)d_in[19];
    const float* DTb = (const float*)d_in[20];
    const float* BPw = (const float*)d_in[21];
    const float* BPb = (const float*)d_in[22];
    const float* CPw = (const float*)d_in[23];
    const float* CPb = (const float*)d_in[24];
    const float* ALg = (const float*)d_in[25];
    const float* DV  = (const float*)d_in[26];
    const float* OWw = (const float*)d_in[27];
    const float* OWb = (const float*)d_in[28];
    const float* QWw = (const float*)d_in[29];
    const float* KWw = (const float*)d_in[30];
    const float* GB  = (const float*)d_in[31];

    char* w = (char*)d_ws;
    float* R0    = (float*)(w + 0);                  // [32768,256] f32 pre-LN scratch
    bf16*  XCATb = (bf16*)(w + 32 * MBYTE);          // [32768,512] x|agg2
    bf16*  AGG1b = (bf16*)(w + 64 * MBYTE);          // [32768,256]; later M2b, OUTb
    bf16*  M2b   = (bf16*)(w + 64 * MBYTE);
    bf16*  OUTb  = (bf16*)(w + 64 * MBYTE);
    bf16*  X1b   = (bf16*)(w + 80 * MBYTE);          // [32768,512]
    bf16*  Gb    = (bf16*)(w + 112 * MBYTE);         // [32768,512] gate -> Y
    bf16*  X2b   = (bf16*)(w + 144 * MBYTE);         // [32768,256] bf16 residual
    bf16*  Qb    = (bf16*)(w + 144 * MBYTE);         // over dead X2b
    bf16*  Kb    = (bf16*)(w + 160 * MBYTE);
    bf16*  XNb   = (bf16*)(w + 176 * MBYTE);         // [32768,256]
    float* DBC   = (float*)(w + 192 * MBYTE);        // [32768,48] f32
    unsigned short* IDX = (unsigned short*)(w + 198 * MBYTE);  // [32768][128]
    int*   CNT   = (int*)(w + 206 * MBYTE);
    float* BASE1 = (float*)(w + 207 * MBYTE);        // [1024,256] f32
    bf16*  PEb   = (bf16*)(w + 208 * MBYTE);
    bf16*  M1b   = (bf16*)(w + 208 * MBYTE + 524288);
    bf16*  WT    = (bf16*)(w + 209 * MBYTE);
    float* B48   = (float*)(w + 211 * MBYTE);

    bf16* P1wT  = WT + 0;
    bf16* U1wT  = WT + 65536;
    bf16* P2wT  = WT + 196608;
    bf16* U2wT  = WT + 262144;
    bf16* INwT  = WT + 393216;
    bf16* DTwT  = WT + 655360;
    bf16* OWwT  = WT + 663552;
    bf16* QWwT  = WT + 794624;
    bf16* KWwT  = WT + 860160;
    bf16* DBCwT = WT + 925696;

    float* out0       = (float*)d_out;
    float* out_probs  = out0 + (long)T_ * N_ * H_;
    float* out_logits = out_probs + (long)T_ * N_ * N_;

    const int RN = T_ * N_;
    dim3 blk(256);
    const float* fnull = nullptr;
    float* f32null = nullptr;
    bf16*  b16null = nullptr;
    const bf16* cb16null = nullptr;

    // ---- prep: pe + 13 transposes + pack48 + idx_build in ONE launch ----
    PrepArgs P;
    P.t[0]  = {P1w, 256, 256,  P1wT, 256, 1.0f};
    P.t[1]  = {U1w, 512, 256,  U1wT, 512, 1.0f};
    P.t[2]  = {P2w, 256, 256,  P2wT, 256, 1.0f};
    P.t[3]  = {U2w, 512, 256,  U2wT, 512, 1.0f};
    P.t[4]  = {INw, 256, 1024, INwT, 256, 1.0f};
    P.t[5]  = {DTw, 16,  512,  DTwT, 16, 1.0f};
    P.t[6]  = {OWw, 512, 256,  OWwT, 512, 1.0f};
    P.t[7]  = {QWw, 256, 256,  QWwT, 256, 0.0625f};   // fold score scale into q
    P.t[8]  = {KWw, 256, 256,  KWwT, 256, 1.0f};
    P.t[9]  = {DLw, 512, 16,   DBCwT, 512, 1.0f};
    P.t[10] = {BPw, 512, 16,   DBCwT + 16 * 512, 512, 1.0f};
    P.t[11] = {CPw, 512, 16,   DBCwT + 32 * 512, 512, 1.0f};
    P.t[12] = {DLw, 1,   1,    DBCwT, 512, 1.0f};     // dummy
    P.pe = PEb; P.pa = DLb; P.pb = BPb; P.pc = CPb; P.po = B48;
    P.adj = adj; P.IDX = IDX; P.CNT = CNT;
    hipLaunchKernelGGL(prep_kernel, dim3(32, 32, 47), blk, 0, stream, P);

    // ---- m1 (z0) ; base1 (z1) ----
    hipLaunchKernelGGL((mfma_gemm128<0, false>), dim3(2, 8, 2), blk, 0, stream,
                       PEb, 256, P1wT, U1wT, 256, 512,
                       f32null, BASE1, M1b, b16null, 256, 256, P1b, U1b, cb16null);

    // ---- agg1 ----
    hipLaunchKernelGGL(agg_gather, dim3(RN), blk, 0, stream, IDX, CNT, M1b, 0L, AGG1b, 256, 0);

    // ---- x-pre = agg1 @ U1[256:] ; then ln1 -> XCAT[:, :256] ----
    hipLaunchKernelGGL((mfma_gemm128<0, false>), dim3(2, 256, 1), blk, 0, stream,
                       AGG1b, 256, U1wT + 256, U1wT + 256, 512, 512,
                       R0, f32null, b16null, b16null, 256, 256, fnull, fnull, cb16null);
    hipLaunchKernelGGL(row_ln1, dim3(RN / 4), blk, 0, stream, R0, BASE1, L1g, L1b, XCATb, RN);

    // ---- m2 ----
    hipLaunchKernelGGL((mfma_gemm128<0, false>), dim3(2, 256, 1), blk, 0, stream,
                       XCATb, 512, P2wT, P2wT, 256, 256,
                       f32null, f32null, M2b, b16null, 256, 256, P2b, fnull, cb16null);

    // ---- agg2 -> XCAT[:, 256:512] ----
    hipLaunchKernelGGL(agg_gather, dim3(RN), blk, 0, stream, IDX, CNT, M2b,
                       (long)N_ * 256, XCATb, 512, 256);

    // ---- x2-pre = [x|agg2] @ U2 + U2b ; dbl_ln -> X2b (bf16), XNb ----
    hipLaunchKernelGGL((mfma_gemm128<0, false>), dim3(2, 256, 1), blk, 0, stream,
                       XCATb, 512, U2wT, U2wT, 512, 512,
                       R0, f32null, b16null, b16null, 256, 512, U2b, fnull, cb16null);
    hipLaunchKernelGGL(dbl_ln, dim3(RN / 4), blk, 0, stream,
                       R0, L2g, L2b, MBg, MBb, X2b, XNb, RN);

    // ---- x1 (z0) ; gate (z1), fused silu ----
    hipLaunchKernelGGL((mfma_gemm128<1, false>), dim3(4, 256, 2), blk, 0, stream,
                       XNb, 256, INwT, INwT + 512 * 256, 256, 256,
                       f32null, f32null, X1b, Gb, 512, 256, INb, INb + 512, cb16null);

    // ---- [d1|B|C] = x1 @ [dw|bw|cw] + b48 ----
    hipLaunchKernelGGL(mfma_gemm64, dim3(1, 512), blk, 0, stream,
                       X1b, 512, DBCwT, 512, DBC, 48, RN, 48, 512, B48);

    // ---- barrier-free scan with fused delta (Y overwrites Gb) ----
    hipLaunchKernelGGL(scan2, dim3(N_), dim3(512), 0, stream,
                       X1b, Gb, DBC, DTwT, DTb, ALg, DV);

    // ---- outs = y @ out_w + out_b + x2 -> out0 (f32, NT) + OUTb (bf16) ----
    hipLaunchKernelGGL((mfma_gemm128<0, true>), dim3(2, 256, 1), blk, 0, stream,
                       Gb, 512, OWwT, OWwT, 512, 512,
                       out0, f32null, OUTb, b16null, 256, 512, OWb, fnull, X2b);

    // ---- q (z0, pre-scaled), k (z1) ----
    hipLaunchKernelGGL((mfma_gemm128<0, false>), dim3(2, 256, 2), blk, 0, stream,
                       OUTb, 256, QWwT, KWwT, 256, 256,
                       f32null, f32null, Qb, Kb, 256, 256, fnull, fnull, cb16null);

    // ---- logits/probs ----
    hipLaunchKernelGGL(score_mfma128, dim3(8, 8, T_), blk, 0, stream,
                       Qb, Kb, out_probs, out_logits, GB);
}